// Round 8
// baseline (122.485 us; speedup 1.0000x reference)
//
#include <hip/hip_runtime.h>

#define NP 4096
#define NSLAB 64
#define ZSPAN 10        // slab 1/64; |dz| < 0.15 (0.05 cube + 0.1 radius) => +/-10 slabs
#define EPS_K 1e-12f
#define MAXH 256        // per-wave hit-list capacity (16 reserved as pipeline pads)

// ---------- prep 1: per-batch histogram + scan + cursor init (1 block/batch) ----------
__global__ __launch_bounds__(1024) void k_bins(const float* __restrict__ locs,
                                               int* __restrict__ off,
                                               int* __restrict__ cursor) {
    __shared__ int s_cnt[NSLAB];
    const int b = blockIdx.x;
    const int tid = threadIdx.x;
    if (tid < NSLAB) s_cnt[tid] = 0;
    __syncthreads();
    const float* lz = locs + (size_t)b * NP * 3;
    for (int i = tid; i < NP; i += 1024) {
        float z = lz[i * 3 + 2];
        int c = min(max((int)(z * 64.0f), 0), 63);
        atomicAdd(&s_cnt[c], 1);
    }
    __syncthreads();
    if (tid < 64) {
        int incl = s_cnt[tid];
        for (int d = 1; d < 64; d <<= 1) {
            int o = __shfl_up(incl, d, 64);
            if (tid >= d) incl += o;
        }
        off[b * (NSLAB + 1) + tid + 1] = incl;
        if (tid == 0) off[b * (NSLAB + 1)] = 0;
        cursor[b * NSLAB + tid] = 0;
    }
}

// ---------- prep 2: scatter into sorted order + weight transpose ----------
__global__ __launch_bounds__(256) void k_scatter(
    const float* __restrict__ locs, const float* __restrict__ data,
    const float* __restrict__ density, const float* __restrict__ weight,
    const int* __restrict__ off, int* __restrict__ cursor,
    float4* __restrict__ slocs, float4* __restrict__ snd, float* __restrict__ wT)
{
    const int tid = threadIdx.x;
    const int b = blockIdx.x >> 4;                     // 16 blocks per batch (NP/256)
    const int il = ((blockIdx.x & 15) << 8) + tid;     // in-batch particle index
    const size_t gi = ((size_t)b << 12) + il;
    const float* lp = locs + gi * 3;
    const float x = lp[0], y = lp[1], z = lp[2];
    const int bin = min(max((int)(z * 64.0f), 0), 63);
    const int r = atomicAdd(&cursor[b * NSLAB + bin], 1);
    const int pos = off[b * (NSLAB + 1) + bin] + r;
    const size_t gp = ((size_t)b << 12) + pos;

    float4 s4 = { x, y, z, __int_as_float(il) };
    slocs[gp] = s4;
    const float invr = 1.0f / density[gi];
    const float4* dsrc = (const float4*)data + (gi << 2);
    float4* ddst = snd + (gp << 2);
#pragma unroll
    for (int q = 0; q < 4; ++q) {
        float4 v = dsrc[q];
        float4 o4 = { v.x * invr, v.y * invr, v.z * invr, v.w * invr };
        ddst[q] = o4;
    }

    if (blockIdx.x == 0) {
        for (int i2 = tid; i2 < 27 * 256; i2 += 256) {
            int k = i2 >> 8, oc = i2 & 255;
            wT[k * 256 + oc] = weight[oc * 27 + k];
        }
    }
}

// ---------- main: wave = 1 particle; scan->LDS hit list; SW-pipelined process ----------
__global__ __launch_bounds__(256, 4) void k_main(
    const float4* __restrict__ slocs,  // [B*NP] sorted {x,y,z,orig}
    const float4* __restrict__ snd,    // [B*NP][4] sorted data/rho
    const int* __restrict__ off,       // [B][65]
    const float* __restrict__ wT,      // [27][16][16]
    const float* __restrict__ bias,
    float* __restrict__ out)
{
    __shared__ float4 s_hits[4][MAXH];          // 16 KB: per-wave hit list

    const int tid  = threadIdx.x;
    const int wid  = tid >> 6;                   // wave in block (4 particles/block)
    const int lane = tid & 63;
    const int hsh  = lane & 32;                  // which half
    const int l32  = lane & 31;                  // k-cell role

    const int bid = blockIdx.x;
    const int b   = bid >> 10;                   // 1024 blocks per batch
    const int p   = ((bid & 1023) << 2) + wid;   // sorted position

    const float4* slb  = slocs + ((size_t)b << 12);
    const float4* sndb = snd   + ((size_t)b << 14);
    const int*    offb = off + b * (NSLAB + 1);
    float4* hl = s_hits[wid];

    const float4 me = slb[p];
    const int orig = __float_as_int(me.w);
    const int sp = min(max((int)(me.z * 64.0f), 0), 63);
    const int jstart = offb[max(sp - ZSPAN, 0)];
    const int jend   = offb[min(sp + ZSPAN, NSLAB - 1) + 1];

    // this lane's kernel-cell center; lanes 27..31 of each half never match (w->0)
    float cx, cy, cz;
    {
        int kk = (l32 < 27) ? l32 : 13;
        cx = me.x + (float)(kk / 9       - 1) * 0.05f;
        cy = me.y + (float)((kk / 3) % 3 - 1) * 0.05f;
        cz = me.z + (float)(kk % 3       - 1) * 0.05f;
        if (l32 >= 27) cx = 1e9f;
    }

    // ---- phase A: scan window, build hit list in LDS (no divergent loop) ----
    int nh = 0;
    const int nsteps = (jend - jstart + 63) >> 6;
    for (int st = 0; st < nsteps; ++st) {
        const int j = jstart + (st << 6) + lane;
        float4 lj = slb[min(j, jend - 1)];
        if (j >= jend) lj.x = 1e9f;
        // box prefilter: distance from candidate j to i's dilated cell cube
        const float ex = fmaxf(fabsf(me.x - lj.x) - 0.05f, 0.f);
        const float ey = fmaxf(fabsf(me.y - lj.y) - 0.05f, 0.f);
        const float ez = fmaxf(fabsf(me.z - lj.z) - 0.05f, 0.f);
        const float bd2 = ex * ex + ey * ey + ez * ez;
        const bool pred = bd2 < 0.01f;
        const unsigned long long ball = __ballot(pred);
        const int pos = nh + (int)__popcll(ball & ((1ull << lane) - 1ull));
        if (pred && pos < MAXH - 16) {
            float4 rec = { lj.x, lj.y, lj.z, __int_as_float(j) };
            hl[pos] = rec;
        }
        nh += (int)__popcll(ball);
    }
    nh = min(nh, MAXH - 16);
    if (lane < 16) {                              // pad records: w evaluates to 0, j=0 valid
        float4 padr = { 1e9f, 1e9f, 1e9f, __int_as_float(0) };
        hl[nh + lane] = padr;
    }

    // ---- phase B: software-pipelined pair loop; halves take alternating entries ----
    // entry m of this half = hl[2m + hoff]; pair t = entries (2t, 2t+1).
    // iter t: issue loads for pair t+1, prefetch records for pair t+2, consume pair t.
    float kv[16];
#pragma unroll
    for (int c = 0; c < 16; ++c) kv[c] = 0.f;

    const int hoff = hsh >> 5;                    // 0 or 1
    const int nt = (nh + 1) >> 1;                 // entries for this half (pads absorb odd)
    const int npairs = (nt + 1) >> 1;

#define ENT(m) hl[((m) << 1) + hoff]
    float4 recA  = ENT(0), recB  = ENT(1);        // pair 0 records
    float4 recA2 = ENT(2), recB2 = ENT(3);        // pair 1 records
    {   // pair 0 data loads (in flight entering the loop)
    }
    const float4* dp0A = sndb + ((size_t)__float_as_int(recA.w) << 2);
    const float4* dp0B = sndb + ((size_t)__float_as_int(recB.w) << 2);
    float4 a0 = dp0A[0], a1 = dp0A[1], a2 = dp0A[2], a3 = dp0A[3];
    float4 b0 = dp0B[0], b1 = dp0B[1], b2 = dp0B[2], b3 = dp0B[3];

    for (int t = 0; t < npairs; ++t) {
        // issue NEXT pair's 8 loads (consumed next iteration -> loop-carried, must stay live)
        const float4* dpA2 = sndb + ((size_t)__float_as_int(recA2.w) << 2);
        const float4* dpB2 = sndb + ((size_t)__float_as_int(recB2.w) << 2);
        const float4 na0 = dpA2[0], na1 = dpA2[1], na2 = dpA2[2], na3 = dpA2[3];
        const float4 nb0 = dpB2[0], nb1 = dpB2[1], nb2 = dpB2[2], nb3 = dpB2[3];
        // prefetch pair t+2's records from LDS
        const float4 recA3 = ENT((t << 1) + 4);
        const float4 recB3 = ENT((t << 1) + 5);

        // consume current pair (data loaded last iteration)
        const float dxA = cx - recA.x, dyA = cy - recA.y, dzA = cz - recA.z;
        const float dxB = cx - recB.x, dyB = cy - recB.y, dzB = cz - recB.z;
        const float d2A = dxA * dxA + dyA * dyA + dzA * dzA;
        const float d2B = dxB * dxB + dyB * dyB + dzB * dzB;
        const float dA = sqrtf(fmaxf(d2A, EPS_K));
        const float dB = sqrtf(fmaxf(d2B, EPS_K));
        float tA = fmaxf(__builtin_fmaf(dA, -10.f, 1.f), 0.f);   // max(1-d/R,0)
        float tB = fmaxf(__builtin_fmaf(dB, -10.f, 1.f), 0.f);
        const float wA = tA * tA * tA;
        const float wB = tB * tB * tB;

        kv[ 0] = fmaf(wB, b0.x, fmaf(wA, a0.x, kv[ 0]));
        kv[ 1] = fmaf(wB, b0.y, fmaf(wA, a0.y, kv[ 1]));
        kv[ 2] = fmaf(wB, b0.z, fmaf(wA, a0.z, kv[ 2]));
        kv[ 3] = fmaf(wB, b0.w, fmaf(wA, a0.w, kv[ 3]));
        kv[ 4] = fmaf(wB, b1.x, fmaf(wA, a1.x, kv[ 4]));
        kv[ 5] = fmaf(wB, b1.y, fmaf(wA, a1.y, kv[ 5]));
        kv[ 6] = fmaf(wB, b1.z, fmaf(wA, a1.z, kv[ 6]));
        kv[ 7] = fmaf(wB, b1.w, fmaf(wA, a1.w, kv[ 7]));
        kv[ 8] = fmaf(wB, b2.x, fmaf(wA, a2.x, kv[ 8]));
        kv[ 9] = fmaf(wB, b2.y, fmaf(wA, a2.y, kv[ 9]));
        kv[10] = fmaf(wB, b2.z, fmaf(wA, a2.z, kv[10]));
        kv[11] = fmaf(wB, b2.w, fmaf(wA, a2.w, kv[11]));
        kv[12] = fmaf(wB, b3.x, fmaf(wA, a3.x, kv[12]));
        kv[13] = fmaf(wB, b3.y, fmaf(wA, a3.y, kv[13]));
        kv[14] = fmaf(wB, b3.z, fmaf(wA, a3.z, kv[14]));
        kv[15] = fmaf(wB, b3.w, fmaf(wA, a3.w, kv[15]));

        // rotate pipeline registers
        recA = recA2; recB = recB2; recA2 = recA3; recB2 = recB3;
        a0 = na0; a1 = na1; a2 = na2; a3 = na3;
        b0 = nb0; b1 = nb1; b2 = nb2; b3 = nb3;
    }
#undef ENT

    // merge the two halves' partial kv (lockstep within the wave)
#pragma unroll
    for (int c = 0; c < 16; ++c)
        kv[c] += __shfl_xor(kv[c], 32, 64);

    // contraction: out[o] = bias[o] + sum_k sum_c wT[k][o][c]*kv[k][c]
    const int kk = (l32 < 27) ? l32 : 26;         // idle lanes carry kv==0
    const float4* wrow = (const float4*)(wT + kk * 256);
    float res = 0.f;
#pragma unroll
    for (int o = 0; o < 16; ++o) {
        const float4 w0 = wrow[o * 4 + 0], w1 = wrow[o * 4 + 1];
        const float4 w2 = wrow[o * 4 + 2], w3 = wrow[o * 4 + 3];
        float acc = 0.f;
        acc = fmaf(w0.x, kv[ 0], acc); acc = fmaf(w0.y, kv[ 1], acc);
        acc = fmaf(w0.z, kv[ 2], acc); acc = fmaf(w0.w, kv[ 3], acc);
        acc = fmaf(w1.x, kv[ 4], acc); acc = fmaf(w1.y, kv[ 5], acc);
        acc = fmaf(w1.z, kv[ 6], acc); acc = fmaf(w1.w, kv[ 7], acc);
        acc = fmaf(w2.x, kv[ 8], acc); acc = fmaf(w2.y, kv[ 9], acc);
        acc = fmaf(w2.z, kv[10], acc); acc = fmaf(w2.w, kv[11], acc);
        acc = fmaf(w3.x, kv[12], acc); acc = fmaf(w3.y, kv[13], acc);
        acc = fmaf(w3.z, kv[14], acc); acc = fmaf(w3.w, kv[15], acc);
#pragma unroll
        for (int dsh = 16; dsh >= 1; dsh >>= 1)
            acc += __shfl_xor(acc, dsh, 32);
        if (l32 == o) res = acc;
    }
    if (lane < 16)
        out[(((size_t)(b << 12)) + orig) * 16 + lane] = res + bias[lane];
}

extern "C" void kernel_launch(void* const* d_in, const int* in_sizes, int n_in,
                              void* d_out, int out_size, void* d_ws, size_t ws_size,
                              hipStream_t stream) {
    const float* locs    = (const float*)d_in[0];
    const float* data    = (const float*)d_in[1];
    const float* density = (const float*)d_in[2];
    const float* weight  = (const float*)d_in[3];
    const float* bias    = (const float*)d_in[4];
    float* out = (float*)d_out;

    const int B = in_sizes[2] / NP;
    const int totalP = B * NP;

    char* ws = (char*)d_ws;
    size_t o = 0;
    auto take = [&](size_t bytes) { size_t r = o; o = (o + bytes + 255) & ~(size_t)255; return r; };
    float4* slocs  = (float4*)(ws + take((size_t)totalP * 16));
    float4* snd    = (float4*)(ws + take((size_t)totalP * 64));
    float*  wT     = (float*)(ws + take(27 * 256 * 4));
    int*    cursor = (int*)(ws + take((size_t)B * NSLAB * 4));
    int*    off    = (int*)(ws + take((size_t)B * (NSLAB + 1) * 4));

    k_bins<<<B, 1024, 0, stream>>>(locs, off, cursor);
    k_scatter<<<totalP / 256, 256, 0, stream>>>(locs, data, density, weight,
                                                off, cursor, slocs, snd, wT);
    k_main<<<B * 1024, 256, 0, stream>>>(slocs, snd, off, wT, bias, out);
}

// Round 9
// 102.681 us; speedup vs baseline: 1.1929x; 1.1929x over previous
//
#include <hip/hip_runtime.h>

#define NP 4096
#define NSLAB 64
#define ZSPAN 10        // slab 1/64; |dz| < 0.15 (0.05 cube + 0.1 radius) => +/-10 slabs
#define EPS_K 1e-12f

// ---------- prep 1: per-batch histogram + scan + cursor init (1 block/batch) ----------
__global__ __launch_bounds__(1024) void k_bins(const float* __restrict__ locs,
                                               int* __restrict__ off,
                                               int* __restrict__ cursor) {
    __shared__ int s_cnt[NSLAB];
    const int b = blockIdx.x;
    const int tid = threadIdx.x;
    if (tid < NSLAB) s_cnt[tid] = 0;
    __syncthreads();
    const float* lz = locs + (size_t)b * NP * 3;
    for (int i = tid; i < NP; i += 1024) {
        float z = lz[i * 3 + 2];
        int c = min(max((int)(z * 64.0f), 0), 63);
        atomicAdd(&s_cnt[c], 1);
    }
    __syncthreads();
    if (tid < 64) {
        int incl = s_cnt[tid];
        for (int d = 1; d < 64; d <<= 1) {
            int o = __shfl_up(incl, d, 64);
            if (tid >= d) incl += o;
        }
        off[b * (NSLAB + 1) + tid + 1] = incl;
        if (tid == 0) off[b * (NSLAB + 1)] = 0;
        cursor[b * NSLAB + tid] = 0;
    }
}

// ---------- prep 2: scatter into sorted order + weight transpose ----------
__global__ __launch_bounds__(256) void k_scatter(
    const float* __restrict__ locs, const float* __restrict__ data,
    const float* __restrict__ density, const float* __restrict__ weight,
    const int* __restrict__ off, int* __restrict__ cursor,
    float4* __restrict__ slocs, float4* __restrict__ snd, float* __restrict__ wT)
{
    const int tid = threadIdx.x;
    const int b = blockIdx.x >> 4;                     // 16 blocks per batch (NP/256)
    const int il = ((blockIdx.x & 15) << 8) + tid;     // in-batch particle index
    const size_t gi = ((size_t)b << 12) + il;
    const float* lp = locs + gi * 3;
    const float x = lp[0], y = lp[1], z = lp[2];
    const int bin = min(max((int)(z * 64.0f), 0), 63);
    const int r = atomicAdd(&cursor[b * NSLAB + bin], 1);
    const int pos = off[b * (NSLAB + 1) + bin] + r;
    const size_t gp = ((size_t)b << 12) + pos;

    float4 s4 = { x, y, z, __int_as_float(il) };
    slocs[gp] = s4;
    const float invr = 1.0f / density[gi];
    const float4* dsrc = (const float4*)data + (gi << 2);
    float4* ddst = snd + (gp << 2);
#pragma unroll
    for (int q = 0; q < 4; ++q) {
        float4 v = dsrc[q];
        float4 o4 = { v.x * invr, v.y * invr, v.z * invr, v.w * invr };
        ddst[q] = o4;
    }

    if (blockIdx.x == 0) {
        for (int i2 = tid; i2 < 27 * 256; i2 += 256) {
            int k = i2 >> 8, oc = i2 & 255;
            wT[k * 256 + oc] = weight[oc * 27 + k];
        }
    }
}

// ---------- main: wave = 1 particle; fused scan+process, shfl chain-head ----------
__global__ __launch_bounds__(256) void k_main(
    const float4* __restrict__ slocs,  // [B*NP] sorted {x,y,z,orig}
    const float4* __restrict__ snd,    // [B*NP][4] sorted data/rho
    const int* __restrict__ off,       // [B][65]
    const float* __restrict__ wT,      // [27][16][16]
    const float* __restrict__ bias,
    float* __restrict__ out)
{
    const int tid  = threadIdx.x;
    const int wid  = tid >> 6;           // wave in block (4 particles/block)
    const int lane = tid & 63;
    const int hsh  = lane & 32;          // 0 or 32: which half
    const int l32  = lane & 31;          // k-cell role within half
    const int hoff = hsh >> 5;           // 0 or 1

    const int bid = blockIdx.x;
    const int b   = bid >> 10;           // 1024 blocks per batch
    const int p   = ((bid & 1023) << 2) + wid;   // sorted position

    const float4* slb  = slocs + ((size_t)b << 12);
    const float4* sndb = snd   + ((size_t)b << 14);
    const int*    offb = off + b * (NSLAB + 1);

    const float4 me = slb[p];
    const int orig = __float_as_int(me.w);
    const int sp = min(max((int)(me.z * 64.0f), 0), 63);
    const int jstart = offb[max(sp - ZSPAN, 0)];
    const int jend   = offb[min(sp + ZSPAN, NSLAB - 1) + 1];

    // this lane's kernel-cell center; lanes 27..31 of each half never match
    float cx, cy, cz;
    {
        int kk = (l32 < 27) ? l32 : 13;
        cx = me.x + (float)(kk / 9       - 1) * 0.05f;
        cy = me.y + (float)((kk / 3) % 3 - 1) * 0.05f;
        cz = me.z + (float)(kk % 3       - 1) * 0.05f;
        if (l32 >= 27) cx = 1e9f;
    }

    float kv[16];
#pragma unroll
    for (int c = 0; c < 16; ++c) kv[c] = 0.f;

    // depth-2 prefetched scan over the window, 64 candidates per step
    const int nsteps = (jend - jstart + 63) >> 6;
    float4 cur, nxt;
    {
        const int j0 = jstart + lane;
        cur = slb[min(j0, jend - 1)];
        if (j0 >= jend) cur.x = 1e9f;
        const int j1 = jstart + 64 + lane;
        nxt = slb[min(j1, jend - 1)];
        if (j1 >= jend) nxt.x = 1e9f;
    }

    for (int st = 0; st < nsteps; ++st) {
        const int tbase = jstart + (st << 6);
        // issue tile st+2 (consumed two iterations later)
        const int j2 = tbase + 128 + lane;
        float4 t2 = slb[min(j2, jend - 1)];
        if (j2 >= jend) t2.x = 1e9f;

        // box prefilter: distance from candidate j to i's dilated cell cube
        const float ex = fmaxf(fabsf(me.x - cur.x) - 0.05f, 0.f);
        const float ey = fmaxf(fabsf(me.y - cur.y) - 0.05f, 0.f);
        const float ez = fmaxf(fabsf(me.z - cur.z) - 0.05f, 0.f);
        const float bd2 = ex * ex + ey * ey + ez * ez;
        const unsigned long long ball = __ballot(bd2 < 0.01f);
        unsigned int mh = (unsigned int)(ball >> hsh);   // this half's 32 bits
        const int cbase = tbase + hsh;

        while (mh) {
            const int bit = __ffs(mh) - 1;
            mh &= mh - 1;
            const int j = cbase + bit;
            // nd loads first: address depends only on the ballot bit -> issue now
            const float4* dp = sndb + ((size_t)j << 2);
            const float4 v0 = dp[0], v1 = dp[1], v2 = dp[2], v3 = dp[3];
            // neighbor coords from the scan register (lgkm ~25cy, overlaps vm)
            const float qx = __shfl(cur.x, bit, 32);
            const float qy = __shfl(cur.y, bit, 32);
            const float qz = __shfl(cur.z, bit, 32);
            const float dx = cx - qx, dy = cy - qy, dz = cz - qz;
            const float d2 = dx * dx + dy * dy + dz * dz;
            const float d = sqrtf(fmaxf(d2, EPS_K));
            float t1 = fmaxf(__builtin_fmaf(d, -10.f, 1.f), 0.f);  // max(1-d/R,0)
            const float w = t1 * t1 * t1;
            kv[ 0] = fmaf(w, v0.x, kv[ 0]);
            kv[ 1] = fmaf(w, v0.y, kv[ 1]);
            kv[ 2] = fmaf(w, v0.z, kv[ 2]);
            kv[ 3] = fmaf(w, v0.w, kv[ 3]);
            kv[ 4] = fmaf(w, v1.x, kv[ 4]);
            kv[ 5] = fmaf(w, v1.y, kv[ 5]);
            kv[ 6] = fmaf(w, v1.z, kv[ 6]);
            kv[ 7] = fmaf(w, v1.w, kv[ 7]);
            kv[ 8] = fmaf(w, v2.x, kv[ 8]);
            kv[ 9] = fmaf(w, v2.y, kv[ 9]);
            kv[10] = fmaf(w, v2.z, kv[10]);
            kv[11] = fmaf(w, v2.w, kv[11]);
            kv[12] = fmaf(w, v3.x, kv[12]);
            kv[13] = fmaf(w, v3.y, kv[13]);
            kv[14] = fmaf(w, v3.z, kv[14]);
            kv[15] = fmaf(w, v3.w, kv[15]);
        }
        cur = nxt;
        nxt = t2;
    }

    // merge the two halves' partial kv (lockstep within the wave)
#pragma unroll
    for (int c = 0; c < 16; ++c)
        kv[c] += __shfl_xor(kv[c], 32, 64);

    // contraction, split across halves: half h computes outputs h*8 .. h*8+7
    const int kk = (l32 < 27) ? l32 : 26;         // idle lanes carry kv==0
    const int obase = hoff << 3;
    float res = 0.f;
#pragma unroll
    for (int oo = 0; oo < 8; ++oo) {
        const float4* wrow = (const float4*)(wT + kk * 256 + (obase + oo) * 16);
        const float4 w0 = wrow[0], w1 = wrow[1], w2 = wrow[2], w3 = wrow[3];
        float acc = 0.f;
        acc = fmaf(w0.x, kv[ 0], acc); acc = fmaf(w0.y, kv[ 1], acc);
        acc = fmaf(w0.z, kv[ 2], acc); acc = fmaf(w0.w, kv[ 3], acc);
        acc = fmaf(w1.x, kv[ 4], acc); acc = fmaf(w1.y, kv[ 5], acc);
        acc = fmaf(w1.z, kv[ 6], acc); acc = fmaf(w1.w, kv[ 7], acc);
        acc = fmaf(w2.x, kv[ 8], acc); acc = fmaf(w2.y, kv[ 9], acc);
        acc = fmaf(w2.z, kv[10], acc); acc = fmaf(w2.w, kv[11], acc);
        acc = fmaf(w3.x, kv[12], acc); acc = fmaf(w3.y, kv[13], acc);
        acc = fmaf(w3.z, kv[14], acc); acc = fmaf(w3.w, kv[15], acc);
#pragma unroll
        for (int dsh = 16; dsh >= 1; dsh >>= 1)
            acc += __shfl_xor(acc, dsh, 32);
        if (l32 == oo) res = acc;
    }
    if (l32 < 8)
        out[(((size_t)(b << 12)) + orig) * 16 + obase + l32] = res + bias[obase + l32];
}

extern "C" void kernel_launch(void* const* d_in, const int* in_sizes, int n_in,
                              void* d_out, int out_size, void* d_ws, size_t ws_size,
                              hipStream_t stream) {
    const float* locs    = (const float*)d_in[0];
    const float* data    = (const float*)d_in[1];
    const float* density = (const float*)d_in[2];
    const float* weight  = (const float*)d_in[3];
    const float* bias    = (const float*)d_in[4];
    float* out = (float*)d_out;

    const int B = in_sizes[2] / NP;
    const int totalP = B * NP;

    char* ws = (char*)d_ws;
    size_t o = 0;
    auto take = [&](size_t bytes) { size_t r = o; o = (o + bytes + 255) & ~(size_t)255; return r; };
    float4* slocs  = (float4*)(ws + take((size_t)totalP * 16));
    float4* snd    = (float4*)(ws + take((size_t)totalP * 64));
    float*  wT     = (float*)(ws + take(27 * 256 * 4));
    int*    cursor = (int*)(ws + take((size_t)B * NSLAB * 4));
    int*    off    = (int*)(ws + take((size_t)B * (NSLAB + 1) * 4));

    k_bins<<<B, 1024, 0, stream>>>(locs, off, cursor);
    k_scatter<<<totalP / 256, 256, 0, stream>>>(locs, data, density, weight,
                                                off, cursor, slocs, snd, wT);
    k_main<<<B * 1024, 256, 0, stream>>>(slocs, snd, off, wT, bias, out);
}